// Round 1
// baseline (1021.537 us; speedup 1.0000x reference)
//
#include <hip/hip_runtime.h>

#define B 2
#define S 2048
#define D 1024
#define H 16
#define HD 64
#define E (2*D)

// ---------------------------------------------------------------------------
// Kernel 1: qk[m,e] = sum_d enc[m,d]*W[e,d] + bias[e]; split into q / k*0.125
// laid out as [b,h,s,hd] for the attention kernel. 64x64 tile, 4x4/thread.
// ---------------------------------------------------------------------------
__global__ __launch_bounds__(256) void proj_kernel(const float* __restrict__ enc,
                                                   const float* __restrict__ W,
                                                   const float* __restrict__ bias,
                                                   float* __restrict__ qbuf,
                                                   float* __restrict__ kbuf) {
    __shared__ __align__(16) float As[16][68];   // [k][m] k-major
    __shared__ __align__(16) float Bs[16][68];   // [k][e]
    const int m0 = blockIdx.x * 64;              // over B*S = 4096
    const int e0 = blockIdx.y * 64;              // over E = 2048
    const int tid = threadIdx.x;
    const int tx = tid & 15;
    const int ty = tid >> 4;
    const int lr = tid >> 2;          // 0..63: row within tile
    const int lc = (tid & 3) << 2;    // 0,4,8,12: k within K-tile

    float acc[4][4] = {};

    for (int k0 = 0; k0 < D; k0 += 16) {
        const float4 a  = *(const float4*)(enc + (size_t)(m0 + lr) * D + k0 + lc);
        const float4 bv = *(const float4*)(W   + (size_t)(e0 + lr) * D + k0 + lc);
        if (k0) __syncthreads();
        As[lc + 0][lr] = a.x;  As[lc + 1][lr] = a.y;
        As[lc + 2][lr] = a.z;  As[lc + 3][lr] = a.w;
        Bs[lc + 0][lr] = bv.x; Bs[lc + 1][lr] = bv.y;
        Bs[lc + 2][lr] = bv.z; Bs[lc + 3][lr] = bv.w;
        __syncthreads();
        #pragma unroll
        for (int kk = 0; kk < 16; ++kk) {
            float a_[4], b_[4];
            *(float4*)a_ = *(const float4*)&As[kk][ty * 4];
            *(float4*)b_ = *(const float4*)&Bs[kk][tx * 4];
            #pragma unroll
            for (int i = 0; i < 4; ++i)
                #pragma unroll
                for (int j = 0; j < 4; ++j)
                    acc[i][j] += a_[i] * b_[j];
        }
    }

    // epilogue: one 64-wide e-tile == exactly one head, entirely q or k
    const int e_base = e0 + tx * 4;
    const bool isq = (e_base < D);
    const int eh = isq ? e_base : (e_base - D);
    const int h = eh >> 6;
    const int hd = eh & 63;
    const float4 b4 = *(const float4*)(bias + e_base);
    float* dstbuf = isq ? qbuf : kbuf;
    const float sc = isq ? 1.0f : 0.125f;   // 1/sqrt(64), exact power of two
    #pragma unroll
    for (int i = 0; i < 4; ++i) {
        const int m = m0 + ty * 4 + i;
        const int bb = m >> 11;         // m / S
        const int ss = m & (S - 1);     // m % S
        float4 v;
        v.x = (acc[i][0] + b4.x) * sc;
        v.y = (acc[i][1] + b4.y) * sc;
        v.z = (acc[i][2] + b4.z) * sc;
        v.w = (acc[i][3] + b4.w) * sc;
        *(float4*)(dstbuf + ((size_t)(bb * H + h) * S + ss) * HD + hd) = v;
    }
}

// ---------------------------------------------------------------------------
// Kernel 2: raw scores  out[z,t,s] = q[z,t,:] . k[z,s,:]   (k pre-scaled)
// lower-triangle tiles only; upper tiles skipped (softmax writes zeros there).
// ---------------------------------------------------------------------------
__global__ __launch_bounds__(256) void scores_kernel(const float* __restrict__ qbuf,
                                                     const float* __restrict__ kbuf,
                                                     float* __restrict__ out) {
    const int t0 = blockIdx.x * 64;
    const int s0 = blockIdx.y * 64;
    if (s0 > t0 + 63) return;          // tile fully masked — uniform exit
    const int z = blockIdx.z;          // b*H + h
    const float* Q = qbuf + (size_t)z * S * HD;
    const float* K = kbuf + (size_t)z * S * HD;

    __shared__ __align__(16) float As[16][68];
    __shared__ __align__(16) float Bs[16][68];
    const int tid = threadIdx.x;
    const int tx = tid & 15;
    const int ty = tid >> 4;
    const int lr = tid >> 2;
    const int lc = (tid & 3) << 2;

    float acc[4][4] = {};

    for (int k0 = 0; k0 < HD; k0 += 16) {
        const float4 a  = *(const float4*)(Q + (size_t)(t0 + lr) * HD + k0 + lc);
        const float4 bv = *(const float4*)(K + (size_t)(s0 + lr) * HD + k0 + lc);
        if (k0) __syncthreads();
        As[lc + 0][lr] = a.x;  As[lc + 1][lr] = a.y;
        As[lc + 2][lr] = a.z;  As[lc + 3][lr] = a.w;
        Bs[lc + 0][lr] = bv.x; Bs[lc + 1][lr] = bv.y;
        Bs[lc + 2][lr] = bv.z; Bs[lc + 3][lr] = bv.w;
        __syncthreads();
        #pragma unroll
        for (int kk = 0; kk < 16; ++kk) {
            float a_[4], b_[4];
            *(float4*)a_ = *(const float4*)&As[kk][ty * 4];
            *(float4*)b_ = *(const float4*)&Bs[kk][tx * 4];
            #pragma unroll
            for (int i = 0; i < 4; ++i)
                #pragma unroll
                for (int j = 0; j < 4; ++j)
                    acc[i][j] += a_[i] * b_[j];
        }
    }

    #pragma unroll
    for (int i = 0; i < 4; ++i) {
        const int t = t0 + ty * 4 + i;
        float4 v = make_float4(acc[i][0], acc[i][1], acc[i][2], acc[i][3]);
        *(float4*)(out + ((size_t)z * S + t) * S + s0 + tx * 4) = v;
    }
}

// ---------------------------------------------------------------------------
// Kernel 3: in-place causal softmax per row; zeros for s > t.
// One 256-thread block per row (B*H*S = 65536 rows).
// ---------------------------------------------------------------------------
__global__ __launch_bounds__(256) void softmax_kernel(float* __restrict__ out) {
    __shared__ float buf[S];
    __shared__ float red[8];
    const int r = blockIdx.x;
    const int t = r & (S - 1);
    float* row = out + (size_t)r * S;
    const int tid = threadIdx.x;

    // load valid prefix, track local max
    float lmax = -1e30f;
    for (int s = tid; s <= t; s += 256) {
        const float v = row[s];
        buf[s] = v;
        lmax = fmaxf(lmax, v);
    }
    #pragma unroll
    for (int off = 32; off > 0; off >>= 1)
        lmax = fmaxf(lmax, __shfl_down(lmax, off, 64));
    if ((tid & 63) == 0) red[tid >> 6] = lmax;
    __syncthreads();
    const float m = fmaxf(fmaxf(red[0], red[1]), fmaxf(red[2], red[3]));

    // exp + local sum (each thread touches the same buf slots it wrote)
    float lsum = 0.0f;
    for (int s = tid; s <= t; s += 256) {
        const float e = __expf(buf[s] - m);
        buf[s] = e;
        lsum += e;
    }
    #pragma unroll
    for (int off = 32; off > 0; off >>= 1)
        lsum += __shfl_down(lsum, off, 64);
    if ((tid & 63) == 0) red[4 + (tid >> 6)] = lsum;
    __syncthreads();
    const float inv = 1.0f / (red[4] + red[5] + red[6] + red[7]);

    for (int s = tid; s < S; s += 256)
        row[s] = (s <= t) ? buf[s] * inv : 0.0f;
}

extern "C" void kernel_launch(void* const* d_in, const int* in_sizes, int n_in,
                              void* d_out, int out_size, void* d_ws, size_t ws_size,
                              hipStream_t stream) {
    const float* enc  = (const float*)d_in[0];   // (B,S,D) fp32
    const float* W    = (const float*)d_in[1];   // (2D,D)  fp32
    const float* bias = (const float*)d_in[2];   // (2D,)   fp32
    float* out = (float*)d_out;                  // (B,H,S,S) fp32

    float* qbuf = (float*)d_ws;                          // B*H*S*HD fp32 = 16.78 MB
    float* kbuf = qbuf + (size_t)B * H * S * HD;         // another 16.78 MB

    proj_kernel<<<dim3((B * S) / 64, E / 64), 256, 0, stream>>>(enc, W, bias, qbuf, kbuf);
    scores_kernel<<<dim3(S / 64, S / 64, B * H), 256, 0, stream>>>(qbuf, kbuf, out);
    softmax_kernel<<<dim3(B * H * S), 256, 0, stream>>>(out);
}

// Round 2
// 652.015 us; speedup vs baseline: 1.5667x; 1.5667x over previous
//
#include <hip/hip_runtime.h>

#define S 2048
#define D 1024
#define H 16
#define HD 64

typedef _Float16 half8 __attribute__((ext_vector_type(8)));
typedef _Float16 half4v __attribute__((ext_vector_type(4)));
typedef float f32x4 __attribute__((ext_vector_type(4)));

// ---------------------------------------------------------------------------
// K1: fp32 -> fp16 elementwise convert (range-safe: |enc|<~6, |W|<~0.2)
// ---------------------------------------------------------------------------
__global__ __launch_bounds__(256) void cvt_f32_f16(const float* __restrict__ src,
                                                   _Float16* __restrict__ dst, int n4) {
    const int i = blockIdx.x * 256 + threadIdx.x;
    if (i >= n4) return;
    const float4 v = ((const float4*)src)[i];
    half4v h;
    h.x = (_Float16)v.x; h.y = (_Float16)v.y;
    h.z = (_Float16)v.z; h.w = (_Float16)v.w;
    ((half4v*)dst)[i] = h;
}

// ---------------------------------------------------------------------------
// K2: proj GEMM, fp16 MFMA. C[m,e] = sum_d enc[m,d]*W[e,d] (+bias, split q/k).
// 128x128 tile, BK=32, 4 waves each 64x64 (4x4 tiles of 16x16x32).
// LDS layout [sub=k/8][row][8 fp16] -> conflict-free ds_read_b128 frags.
// ---------------------------------------------------------------------------
__global__ __launch_bounds__(256) void proj_mfma(const _Float16* __restrict__ Ah,  // [4096][1024]
                                                 const _Float16* __restrict__ Wh,  // [2048][1024]
                                                 const float* __restrict__ bias,
                                                 _Float16* __restrict__ qbuf,     // [32][2048][64]
                                                 _Float16* __restrict__ kbuf) {
    __shared__ __align__(16) _Float16 As[4][128][8];   // 8 KB
    __shared__ __align__(16) _Float16 Bs[4][128][8];   // 8 KB
    const int tid = threadIdx.x;
    const int w   = tid >> 6;
    const int l   = tid & 63;
    const int l15 = l & 15;
    const int l4  = l >> 4;
    const int wy  = w >> 1;        // 0,1 : row half
    const int wx  = w & 1;         // 0,1 : col half
    const int m0  = blockIdx.x * 128;
    const int n0  = blockIdx.y * 128;

    f32x4 acc[4][4] = {};

    for (int k0 = 0; k0 < D; k0 += 32) {
        if (k0) __syncthreads();
        #pragma unroll
        for (int p = 0; p < 2; ++p) {
            const int slot = p * 256 + tid;
            const int sub = slot >> 7, row = slot & 127;
            *(uint4*)&As[sub][row][0] = *(const uint4*)(Ah + (size_t)(m0 + row) * D + k0 + sub * 8);
            *(uint4*)&Bs[sub][row][0] = *(const uint4*)(Wh + (size_t)(n0 + row) * D + k0 + sub * 8);
        }
        __syncthreads();

        half8 af[4], bf[4];
        #pragma unroll
        for (int i = 0; i < 4; ++i)
            af[i] = *(const half8*)&As[l4][wy * 64 + i * 16 + l15][0];
        #pragma unroll
        for (int j = 0; j < 4; ++j)
            bf[j] = *(const half8*)&Bs[l4][wx * 64 + j * 16 + l15][0];
        #pragma unroll
        for (int i = 0; i < 4; ++i)
            #pragma unroll
            for (int j = 0; j < 4; ++j)
                acc[i][j] = __builtin_amdgcn_mfma_f32_16x16x32_f16(af[i], bf[j], acc[i][j], 0, 0, 0);
    }

    // epilogue: e-column = n0 + wx*64 + j*16 + l15 ; m-row = m0 + wy*64 + i*16 + l4*4 + r
    #pragma unroll
    for (int j = 0; j < 4; ++j) {
        const int e   = n0 + wx * 64 + j * 16 + l15;
        const bool isq = (e < D);
        const int eh  = isq ? e : (e - D);
        const int h   = eh >> 6;
        const int hd  = eh & 63;
        _Float16* dst = isq ? qbuf : kbuf;
        const float sc = isq ? 1.0f : 0.125f;       // 1/sqrt(64), exact
        const float bv = bias[e];
        #pragma unroll
        for (int i = 0; i < 4; ++i) {
            #pragma unroll
            for (int r = 0; r < 4; ++r) {
                const int m  = m0 + wy * 64 + i * 16 + l4 * 4 + r;
                const int bb = m >> 11;             // m / S
                const int ss = m & (S - 1);
                dst[((size_t)(bb * H + h) * S + ss) * HD + hd] = (_Float16)((acc[i][j][r] + bv) * sc);
            }
        }
    }
}

// ---------------------------------------------------------------------------
// K3: fused scores + causal softmax. One block per (z, 64-row t-stripe).
// Pass A: MFMA scores -> online (m,l) per row in registers.
// Pass B: recompute identical scores, write exp(s-m)/l. Then zero upper tri.
// ---------------------------------------------------------------------------
__global__ __launch_bounds__(256) void attn_fused(const _Float16* __restrict__ qbuf,
                                                  const _Float16* __restrict__ kbuf,
                                                  float* __restrict__ out) {
    __shared__ __align__(16) _Float16 Qs[8][64][8];   // 8 KB
    __shared__ __align__(16) _Float16 Ks[8][64][8];   // 8 KB
    const int tid = threadIdx.x;
    const int w   = tid >> 6;
    const int l   = tid & 63;
    const int l15 = l & 15;
    const int l4  = l >> 4;
    const int t0  = blockIdx.x * 64;
    const int z   = blockIdx.y;

    const _Float16* Qg = qbuf + (size_t)z * S * HD;
    const _Float16* Kg = kbuf + (size_t)z * S * HD;
    float* outz = out + (size_t)z * S * S;

    // stage Q tile (64 rows x 64 hd)
    #pragma unroll
    for (int p = 0; p < 2; ++p) {
        const int slot = p * 256 + tid;
        const int sub = slot >> 6, row = slot & 63;
        *(uint4*)&Qs[sub][row][0] = *(const uint4*)(Qg + (size_t)(t0 + row) * HD + sub * 8);
    }
    __syncthreads();
    half8 qf0 = *(const half8*)&Qs[l4][w * 16 + l15][0];
    half8 qf1 = *(const half8*)&Qs[4 + l4][w * 16 + l15][0];

    const int nst = (t0 >> 6) + 1;       // number of s-tiles (s0 <= t0)
    const int trow = t0 + w * 16 + l4 * 4;

    float m_r[4] = {-1e30f, -1e30f, -1e30f, -1e30f};
    float l_r[4] = {0.f, 0.f, 0.f, 0.f};

    // ---------------- PASS A: stats ----------------
    for (int st = 0; st < nst; ++st) {
        const int s0 = st * 64;
        __syncthreads();
        #pragma unroll
        for (int p = 0; p < 2; ++p) {
            const int slot = p * 256 + tid;
            const int sub = slot >> 6, row = slot & 63;
            *(uint4*)&Ks[sub][row][0] = *(const uint4*)(Kg + (size_t)(s0 + row) * HD + sub * 8);
        }
        __syncthreads();

        f32x4 c[4] = {};
        #pragma unroll
        for (int j = 0; j < 4; ++j) {
            const half8 kf0 = *(const half8*)&Ks[l4][j * 16 + l15][0];
            const half8 kf1 = *(const half8*)&Ks[4 + l4][j * 16 + l15][0];
            c[j] = __builtin_amdgcn_mfma_f32_16x16x32_f16(qf0, kf0, c[j], 0, 0, 0);
            c[j] = __builtin_amdgcn_mfma_f32_16x16x32_f16(qf1, kf1, c[j], 0, 0, 0);
        }
        if (s0 == t0) {   // diagonal tile: mask s > t
            #pragma unroll
            for (int j = 0; j < 4; ++j) {
                const int scol = s0 + j * 16 + l15;
                #pragma unroll
                for (int r = 0; r < 4; ++r)
                    if (scol > trow + r) c[j][r] = -1e30f;
            }
        }
        #pragma unroll
        for (int r = 0; r < 4; ++r) {
            float tm = fmaxf(fmaxf(c[0][r], c[1][r]), fmaxf(c[2][r], c[3][r]));
            tm = fmaxf(tm, __shfl_xor(tm, 1, 16));
            tm = fmaxf(tm, __shfl_xor(tm, 2, 16));
            tm = fmaxf(tm, __shfl_xor(tm, 4, 16));
            tm = fmaxf(tm, __shfl_xor(tm, 8, 16));
            const float mnew = fmaxf(m_r[r], tm);
            float sum = __expf(c[0][r] - mnew) + __expf(c[1][r] - mnew)
                      + __expf(c[2][r] - mnew) + __expf(c[3][r] - mnew);
            sum += __shfl_xor(sum, 1, 16);
            sum += __shfl_xor(sum, 2, 16);
            sum += __shfl_xor(sum, 4, 16);
            sum += __shfl_xor(sum, 8, 16);
            l_r[r] = l_r[r] * __expf(m_r[r] - mnew) + sum;
            m_r[r] = mnew;
        }
    }

    float inv_l[4];
    #pragma unroll
    for (int r = 0; r < 4; ++r) inv_l[r] = 1.0f / l_r[r];

    // ---------------- PASS B: recompute + write ----------------
    for (int st = 0; st < nst; ++st) {
        const int s0 = st * 64;
        __syncthreads();
        #pragma unroll
        for (int p = 0; p < 2; ++p) {
            const int slot = p * 256 + tid;
            const int sub = slot >> 6, row = slot & 63;
            *(uint4*)&Ks[sub][row][0] = *(const uint4*)(Kg + (size_t)(s0 + row) * HD + sub * 8);
        }
        __syncthreads();

        f32x4 c[4] = {};
        #pragma unroll
        for (int j = 0; j < 4; ++j) {
            const half8 kf0 = *(const half8*)&Ks[l4][j * 16 + l15][0];
            const half8 kf1 = *(const half8*)&Ks[4 + l4][j * 16 + l15][0];
            c[j] = __builtin_amdgcn_mfma_f32_16x16x32_f16(qf0, kf0, c[j], 0, 0, 0);
            c[j] = __builtin_amdgcn_mfma_f32_16x16x32_f16(qf1, kf1, c[j], 0, 0, 0);
        }
        if (s0 == t0) {
            #pragma unroll
            for (int j = 0; j < 4; ++j) {
                const int scol = s0 + j * 16 + l15;
                #pragma unroll
                for (int r = 0; r < 4; ++r)
                    if (scol > trow + r) c[j][r] = -1e30f;   // exp -> exact 0
            }
        }
        #pragma unroll
        for (int r = 0; r < 4; ++r) {
            float* rowp = outz + (size_t)(trow + r) * S + s0 + l15;
            #pragma unroll
            for (int j = 0; j < 4; ++j)
                rowp[j * 16] = __expf(c[j][r] - m_r[r]) * inv_l[r];
        }
    }

    // ---------------- zero-fill upper triangle rectangle ----------------
    const int zc0 = t0 + 64;            // cols [zc0, S) are zero for all 64 rows
    const int W4 = (S - zc0) >> 2;
    const float4 z4 = make_float4(0.f, 0.f, 0.f, 0.f);
    for (int row = 0; row < 64; ++row) {
        float* rp = outz + (size_t)(t0 + row) * S + zc0;
        for (int c4 = tid; c4 < W4; c4 += 256)
            *(float4*)(rp + c4 * 4) = z4;
    }
}

extern "C" void kernel_launch(void* const* d_in, const int* in_sizes, int n_in,
                              void* d_out, int out_size, void* d_ws, size_t ws_size,
                              hipStream_t stream) {
    const float* enc  = (const float*)d_in[0];   // (2,2048,1024) fp32
    const float* Wf   = (const float*)d_in[1];   // (2048,1024)   fp32
    const float* bias = (const float*)d_in[2];   // (2048,)       fp32
    float* out = (float*)d_out;                  // (2,16,2048,2048) fp32

    _Float16* enc_h = (_Float16*)d_ws;                       // 4,194,304 elems
    _Float16* w_h   = enc_h + (size_t)4096 * 1024;           // 2,097,152
    _Float16* qbuf  = w_h   + (size_t)2048 * 1024;           // 4,194,304
    _Float16* kbuf  = qbuf  + (size_t)32 * 2048 * 64;        // 4,194,304

    const int n4_enc = (4096 * 1024) / 4;
    const int n4_w   = (2048 * 1024) / 4;
    cvt_f32_f16<<<(n4_enc + 255) / 256, 256, 0, stream>>>(enc, enc_h, n4_enc);
    cvt_f32_f16<<<(n4_w   + 255) / 256, 256, 0, stream>>>(Wf, w_h, n4_w);

    proj_mfma<<<dim3(4096 / 128, 2048 / 128), 256, 0, stream>>>(enc_h, w_h, bias, qbuf, kbuf);

    attn_fused<<<dim3(S / 64, 32), 256, 0, stream>>>(qbuf, kbuf, out);
}